// Round 5
// baseline (81.343 us; speedup 1.0000x reference)
//
#include <hip/hip_runtime.h>

#define M_ 256
#define K_ 8192
#define N_ 8192

typedef int v4i __attribute__((ext_vector_type(4)));
typedef int v16i __attribute__((ext_vector_type(16)));

// ---------------- kernel 1: per-token int8 quantization ----------------
// Writes xq in MFMA-A-fragment-tiled layout (bijective byte map, 2 MB):
//   (m,k) -> addr = (mt<<18) + (chunk<<13) + (ks<<10) + (lane<<4) + b
//   mt=m>>5, chunk=k>>8, ks=(k>>5)&7, lane=(m&31)+32*((k>>4)&1), b=k&15
__global__ __launch_bounds__(256) void awq_quant(const float* __restrict__ x,
                                                 signed char* __restrict__ xqt,
                                                 float* __restrict__ scales) {
    const int m = blockIdx.x;
    const int t = threadIdx.x;
    const float4* xrow = (const float4*)(x + (size_t)m * K_);
    float4 v[8];
    float mx = 0.0f;
#pragma unroll
    for (int j = 0; j < 8; ++j) {
        v[j] = xrow[j * 256 + t];
        mx = fmaxf(mx, fmaxf(fmaxf(fabsf(v[j].x), fabsf(v[j].y)),
                             fmaxf(fabsf(v[j].z), fabsf(v[j].w))));
    }
#pragma unroll
    for (int off = 32; off > 0; off >>= 1) mx = fmaxf(mx, __shfl_xor(mx, off, 64));
    __shared__ float red[4];
    if ((t & 63) == 0) red[t >> 6] = mx;
    __syncthreads();
    mx = fmaxf(fmaxf(red[0], red[1]), fmaxf(red[2], red[3]));
    const float scale = fmaxf(mx / 127.0f, 1e-8f);

    char* base = (char*)xqt + ((size_t)(m >> 5) << 18);
    const int ml = m & 31;
#pragma unroll
    for (int j = 0; j < 8; ++j) {
        const int q0 = (int)fminf(fmaxf(rintf(v[j].x / scale), -127.0f), 127.0f);
        const int q1 = (int)fminf(fmaxf(rintf(v[j].y / scale), -127.0f), 127.0f);
        const int q2 = (int)fminf(fmaxf(rintf(v[j].z / scale), -127.0f), 127.0f);
        const int q3 = (int)fminf(fmaxf(rintf(v[j].w / scale), -127.0f), 127.0f);
        const int packed = (q0 & 255) | ((q1 & 255) << 8) | ((q2 & 255) << 16) | ((q3 & 255) << 24);
        const int k0 = 4 * (j * 256 + t);
        const int addr = ((k0 >> 8) << 13) + (((k0 >> 5) & 7) << 10) +
                         ((ml + (((k0 >> 4) & 1) << 5)) << 4) + (k0 & 15);
        *(int*)(base + addr) = packed;
    }
    if (t == 0) scales[m] = scale;
}

// ---------------- kernel 2: int8 GEMM + dequant epilogue ----------------
// grid = 512 blocks, 256 thr = 4 waves. Two blocks per n-slice (same XCD via
// bid%8 pairing) own disjoint m-halves -> 2 independent pipelines per CU fill
// each other's barrier bubbles; qw re-read served by XCD L2 (HBM-neutral).
// 2-stage pipeline, raw barriers (lgkmcnt only, never vmcnt-drain).

__device__ __forceinline__ void stage_b8(char* btn, int bwo, const int4* w) {
#pragma unroll
    for (int j = 0; j < 4; ++j) {
        const unsigned a0 = __builtin_amdgcn_perm((unsigned)((const int*)&w[1])[j], (unsigned)((const int*)&w[0])[j], 0x00000400u);
        const unsigned a1 = __builtin_amdgcn_perm((unsigned)((const int*)&w[3])[j], (unsigned)((const int*)&w[2])[j], 0x00000400u);
        const unsigned b0 = __builtin_amdgcn_perm((unsigned)((const int*)&w[5])[j], (unsigned)((const int*)&w[4])[j], 0x00000400u);
        const unsigned b1 = __builtin_amdgcn_perm((unsigned)((const int*)&w[7])[j], (unsigned)((const int*)&w[6])[j], 0x00000400u);
        uint2 o;
        o.x = __builtin_amdgcn_perm(a1, a0, 0x05040100u);
        o.y = __builtin_amdgcn_perm(b1, b0, 0x05040100u);
        *(uint2*)(btn + bwo + j * 272) = o;
    }
}

__global__ __launch_bounds__(256, 2) void awq_gemm(const signed char* __restrict__ xqt,
                                                   const float* __restrict__ scales,
                                                   const int* __restrict__ qw,
                                                   const float* __restrict__ wscale,
                                                   const float* __restrict__ bias,
                                                   float* __restrict__ out) {
    __shared__ __align__(16) char btile[2][32 * 272];
    const int t = threadIdx.x;
    const int lane = t & 63;
    const int wave = t >> 6;               // 0..3
    const int bid = blockIdx.x;
    // pairing: bid = 16g + 8*mhalf + x ; n_idx = 8g + x ; partners share XCD (bid%8)
    const int mhalf = (bid >> 3) & 1;
    const int n0 = ((bid >> 4) * 8 + (bid & 7)) * 32;

    const int sa = t & 7;                  // n-group: cols n0 + 4*sa + j
    const int sr = t >> 3;                 // 0..31: k rows 8*sr + i
    const int* qbase = qw + (size_t)(8 * sr) * N_ + n0 + 4 * sa;

    // tiled A base: this block's m-tiles are mhalf*4 + wave
    const signed char* xqb = xqt + ((size_t)(mhalf * 4 + wave) << 18) + lane * 16;

    const int bro = (lane & 31) * 272 + (lane >> 5) * 16;
    const int bwo = (4 * sa) * 272 + 8 * sr;

    v16i acc = {};
    v4i aF[8];
    int4 sA[8], sB[8];

    auto loadq = [&](int4* dst, int chunk) {
        const int4* q = (const int4*)(qbase + (size_t)chunk * 256 * N_);
#pragma unroll
        for (int i = 0; i < 8; ++i) dst[i] = q[i * (N_ / 4)];
    };

    // prologue: sA <- chunk0, sB <- chunk1, aF <- chunk0, stage buf0
    loadq(sA, 0);
    loadq(sB, 1);
#pragma unroll
    for (int ks = 0; ks < 8; ++ks) aF[ks] = *(const v4i*)(xqb + ks * 1024);
    stage_b8(&btile[0][0], bwo, sA);
    asm volatile("s_waitcnt lgkmcnt(0)" ::: "memory");
    __builtin_amdgcn_s_barrier();
    __builtin_amdgcn_sched_barrier(0);

    for (int sc = 0; sc < 32; sc += 2) {
        {   // even: compute chunk sc (buf0); stage sc+1 (sB) -> buf1; issue sc+2 -> sA
            const int c2 = (sc + 2 < 32) ? sc + 2 : 31;
            loadq(sA, c2);
            const int an = (sc + 1 < 32) ? sc + 1 : 31;
            const char* btc = &btile[0][0];
#pragma unroll
            for (int ks = 0; ks < 8; ++ks) {
                const v4i bf = *(const v4i*)(btc + bro + ks * 32);
                acc = __builtin_amdgcn_mfma_i32_32x32x32_i8(aF[ks], bf, acc, 0, 0, 0);
                aF[ks] = *(const v4i*)(xqb + an * 8192 + ks * 1024);
            }
            stage_b8(&btile[1][0], bwo, sB);
            asm volatile("s_waitcnt lgkmcnt(0)" ::: "memory");
            __builtin_amdgcn_s_barrier();
            __builtin_amdgcn_sched_barrier(0);
        }
        {   // odd: compute chunk sc+1 (buf1); stage sc+2 (sA) -> buf0; issue sc+3 -> sB
            const int c3 = (sc + 3 < 32) ? sc + 3 : 31;
            loadq(sB, c3);
            const int an = (sc + 2 < 32) ? sc + 2 : 31;
            const char* btc = &btile[1][0];
#pragma unroll
            for (int ks = 0; ks < 8; ++ks) {
                const v4i bf = *(const v4i*)(btc + bro + ks * 32);
                acc = __builtin_amdgcn_mfma_i32_32x32x32_i8(aF[ks], bf, acc, 0, 0, 0);
                aF[ks] = *(const v4i*)(xqb + an * 8192 + ks * 1024);
            }
            stage_b8(&btile[0][0], bwo, sA);
            asm volatile("s_waitcnt lgkmcnt(0)" ::: "memory");
            __builtin_amdgcn_s_barrier();
            __builtin_amdgcn_sched_barrier(0);
        }
    }

    // epilogue: dequant. C/D layout: col=lane&31, row=(g&3)+8*(g>>2)+4*(lane>>5)
    const int n = n0 + (lane & 31);
    const float wn = wscale[n];
    const float bn = bias[n];
    const int mb = (mhalf * 4 + wave) * 32 + 4 * (lane >> 5);
#pragma unroll
    for (int g = 0; g < 16; ++g) {
        const int m = mb + (g & 3) + 8 * (g >> 2);
        out[(size_t)m * N_ + n] = ((float)acc[g] * scales[m]) * wn + bn;
    }
}

extern "C" void kernel_launch(void* const* d_in, const int* in_sizes, int n_in,
                              void* d_out, int out_size, void* d_ws, size_t ws_size,
                              hipStream_t stream) {
    const float* x    = (const float*)d_in[0];
    const int*   qw   = (const int*)d_in[1];
    const float* wsc  = (const float*)d_in[2];
    const float* bias = (const float*)d_in[3];
    float* out = (float*)d_out;

    signed char* xqbuf  = (signed char*)d_ws;                      // 2 MB, tiled
    float*       scales = (float*)((char*)d_ws + (size_t)M_ * K_); // 1 KB

    awq_quant<<<M_, 256, 0, stream>>>(x, xqbuf, scales);
    awq_gemm<<<512, 256, 0, stream>>>(xqbuf, scales, qw, wsc, bias, out);
}

// Round 6
// 63.923 us; speedup vs baseline: 1.2725x; 1.2725x over previous
//
#include <hip/hip_runtime.h>

#define M_ 256
#define K_ 8192
#define N_ 8192

typedef int v4i __attribute__((ext_vector_type(4)));
typedef int v16i __attribute__((ext_vector_type(16)));

// ---------------- kernel 1: per-token int8 quantization ----------------
// Writes xq in MFMA-A-fragment-tiled layout (bijective byte map, 2 MB):
//   (m,k) -> addr = (mt<<18) + (chunk<<13) + (ks<<10) + (lane<<4) + b
//   mt=m>>5, chunk=k>>8, ks=(k>>5)&7, lane=(m&31)+32*((k>>4)&1), b=k&15
__global__ __launch_bounds__(256) void awq_quant(const float* __restrict__ x,
                                                 signed char* __restrict__ xqt,
                                                 float* __restrict__ scales) {
    const int m = blockIdx.x;
    const int t = threadIdx.x;
    const float4* xrow = (const float4*)(x + (size_t)m * K_);
    float4 v[8];
    float mx = 0.0f;
#pragma unroll
    for (int j = 0; j < 8; ++j) {
        v[j] = xrow[j * 256 + t];
        mx = fmaxf(mx, fmaxf(fmaxf(fabsf(v[j].x), fabsf(v[j].y)),
                             fmaxf(fabsf(v[j].z), fabsf(v[j].w))));
    }
#pragma unroll
    for (int off = 32; off > 0; off >>= 1) mx = fmaxf(mx, __shfl_xor(mx, off, 64));
    __shared__ float red[4];
    if ((t & 63) == 0) red[t >> 6] = mx;
    __syncthreads();
    mx = fmaxf(fmaxf(red[0], red[1]), fmaxf(red[2], red[3]));
    const float scale = fmaxf(mx / 127.0f, 1e-8f);

    char* base = (char*)xqt + ((size_t)(m >> 5) << 18);
    const int ml = m & 31;
#pragma unroll
    for (int j = 0; j < 8; ++j) {
        const int q0 = (int)fminf(fmaxf(rintf(v[j].x / scale), -127.0f), 127.0f);
        const int q1 = (int)fminf(fmaxf(rintf(v[j].y / scale), -127.0f), 127.0f);
        const int q2 = (int)fminf(fmaxf(rintf(v[j].z / scale), -127.0f), 127.0f);
        const int q3 = (int)fminf(fmaxf(rintf(v[j].w / scale), -127.0f), 127.0f);
        const int packed = (q0 & 255) | ((q1 & 255) << 8) | ((q2 & 255) << 16) | ((q3 & 255) << 24);
        const int k0 = 4 * (j * 256 + t);
        const int addr = ((k0 >> 8) << 13) + (((k0 >> 5) & 7) << 10) +
                         ((ml + (((k0 >> 4) & 1) << 5)) << 4) + (k0 & 15);
        *(int*)(base + addr) = packed;
    }
    if (t == 0) scales[m] = scale;
}

// ---------------- kernel 2: int8 GEMM + dequant epilogue ----------------
// grid = 256 blocks (1/CU), 512 thr = 8 waves, one 32x32 m-tile per wave.
// Issue order per iteration (pinned): [A-refills (L2, fast)] -> [qw loadq
// (HBM)] -> compute -> stage -> lgkm+barrier. A-refills issued BEFORE the
// HBM loads so vmcnt's in-order retirement never couples MFMA start to HBM
// round-trip; only stage_b's wait throttles (= the HBM stream governor).
// A fragments ping-pong (aE/aO) since refills happen a full chunk early.

__device__ __forceinline__ void stage_b(char* btn, int bwo,
                                        const int4& w0, const int4& w1,
                                        const int4& w2, const int4& w3) {
    const int* p0 = (const int*)&w0;
    const int* p1 = (const int*)&w1;
    const int* p2 = (const int*)&w2;
    const int* p3 = (const int*)&w3;
#pragma unroll
    for (int j = 0; j < 4; ++j) {
        const unsigned u = __builtin_amdgcn_perm((unsigned)p1[j], (unsigned)p0[j], 0x00000400u);
        const unsigned w = __builtin_amdgcn_perm((unsigned)p3[j], (unsigned)p2[j], 0x00000400u);
        const unsigned o = __builtin_amdgcn_perm(w, u, 0x05040100u);
        *(unsigned*)(btn + bwo + j * 272) = o;
    }
}

__global__ __launch_bounds__(512) void awq_gemm(const signed char* __restrict__ xqt,
                                                const float* __restrict__ scales,
                                                const int* __restrict__ qw,
                                                const float* __restrict__ wscale,
                                                const float* __restrict__ bias,
                                                float* __restrict__ out) {
    __shared__ __align__(16) char btile[2][32 * 272];
    const int t = threadIdx.x;
    const int lane = t & 63;
    const int wave = t >> 6;
    const int n0 = blockIdx.x * 32;

    const int sa = t & 7;                  // n-group
    const int sr = t >> 3;                 // k-row group (0..63)
    const int* qbase = qw + (size_t)(4 * sr) * N_ + n0 + 4 * sa;

    // tiled A base: wave's m-tile (256KB each), this lane's 16B slot
    const signed char* xqb = xqt + ((size_t)wave << 18) + lane * 16;

    const int bro = (lane & 31) * 272 + (lane >> 5) * 16;
    const int bwo = (4 * sa) * 272 + 4 * sr;

    v16i acc = {};
    v4i aE[8], aO[8];
    int4 sA[4], sB[4];

    auto loadq = [&](int4* dst, int chunk) {
        const int4* q = (const int4*)(qbase + (size_t)chunk * 256 * N_);
        dst[0] = q[0];
        dst[1] = q[N_ / 4];
        dst[2] = q[2 * (N_ / 4)];
        dst[3] = q[3 * (N_ / 4)];
    };

    // prologue: aE <- chunk0 frags; sA <- chunk0, sB <- chunk1; stage buf0
#pragma unroll
    for (int ks = 0; ks < 8; ++ks) aE[ks] = *(const v4i*)(xqb + ks * 1024);
    loadq(sA, 0);
    loadq(sB, 1);
    stage_b(&btile[0][0], bwo, sA[0], sA[1], sA[2], sA[3]);
    asm volatile("s_waitcnt lgkmcnt(0)" ::: "memory");
    __builtin_amdgcn_s_barrier();
    __builtin_amdgcn_sched_barrier(0);

    for (int sc = 0; sc < 32; sc += 2) {
        {   // even: compute chunk sc (buf0, aE); refill aO<-sc+1; loadq sA<-sc+2;
            // stage sc+1 (sB) -> buf1
            const int ra = (sc + 1 < 32) ? sc + 1 : 31;
#pragma unroll
            for (int ks = 0; ks < 8; ++ks)
                aO[ks] = *(const v4i*)(xqb + ra * 8192 + ks * 1024);
            const int c2 = (sc + 2 < 32) ? sc + 2 : 31;
            loadq(sA, c2);
            __builtin_amdgcn_sched_barrier(0);
            const char* btc = &btile[0][0];
#pragma unroll
            for (int ks = 0; ks < 8; ++ks) {
                const v4i bf = *(const v4i*)(btc + bro + ks * 32);
                acc = __builtin_amdgcn_mfma_i32_32x32x32_i8(aE[ks], bf, acc, 0, 0, 0);
            }
            stage_b(&btile[1][0], bwo, sB[0], sB[1], sB[2], sB[3]);
            asm volatile("s_waitcnt lgkmcnt(0)" ::: "memory");
            __builtin_amdgcn_s_barrier();
            __builtin_amdgcn_sched_barrier(0);
        }
        {   // odd: compute chunk sc+1 (buf1, aO); refill aE<-sc+2; loadq sB<-sc+3;
            // stage sc+2 (sA) -> buf0
            const int ra = (sc + 2 < 32) ? sc + 2 : 31;
#pragma unroll
            for (int ks = 0; ks < 8; ++ks)
                aE[ks] = *(const v4i*)(xqb + ra * 8192 + ks * 1024);
            const int c3 = (sc + 3 < 32) ? sc + 3 : 31;
            loadq(sB, c3);
            __builtin_amdgcn_sched_barrier(0);
            const char* btc = &btile[1][0];
#pragma unroll
            for (int ks = 0; ks < 8; ++ks) {
                const v4i bf = *(const v4i*)(btc + bro + ks * 32);
                acc = __builtin_amdgcn_mfma_i32_32x32x32_i8(aO[ks], bf, acc, 0, 0, 0);
            }
            stage_b(&btile[0][0], bwo, sA[0], sA[1], sA[2], sA[3]);
            asm volatile("s_waitcnt lgkmcnt(0)" ::: "memory");
            __builtin_amdgcn_s_barrier();
            __builtin_amdgcn_sched_barrier(0);
        }
    }

    // epilogue: dequant. C/D layout: col=lane&31, row=(g&3)+8*(g>>2)+4*(lane>>5)
    const int n = n0 + (lane & 31);
    const float wn = wscale[n];
    const float bn = bias[n];
    const int mb = wave * 32 + 4 * (lane >> 5);
#pragma unroll
    for (int g = 0; g < 16; ++g) {
        const int m = mb + (g & 3) + 8 * (g >> 2);
        out[(size_t)m * N_ + n] = ((float)acc[g] * scales[m]) * wn + bn;
    }
}

extern "C" void kernel_launch(void* const* d_in, const int* in_sizes, int n_in,
                              void* d_out, int out_size, void* d_ws, size_t ws_size,
                              hipStream_t stream) {
    const float* x    = (const float*)d_in[0];
    const int*   qw   = (const int*)d_in[1];
    const float* wsc  = (const float*)d_in[2];
    const float* bias = (const float*)d_in[3];
    float* out = (float*)d_out;

    signed char* xqbuf  = (signed char*)d_ws;                      // 2 MB, tiled
    float*       scales = (float*)((char*)d_ws + (size_t)M_ * K_); // 1 KB

    awq_quant<<<M_, 256, 0, stream>>>(x, xqbuf, scales);
    awq_gemm<<<N_ / 32, 512, 0, stream>>>(xqbuf, scales, qw, wsc, bias, out);
}